// Round 1
// baseline (5833.237 us; speedup 1.0000x reference)
//
#include <hip/hip_runtime.h>
#include <hip/hip_bf16.h>

typedef __bf16 bf16_t;
typedef __bf16 bf16x8 __attribute__((ext_vector_type(8)));
typedef __bf16 bf16x4 __attribute__((ext_vector_type(4)));
typedef float f32x4 __attribute__((ext_vector_type(4)));

#define NN 50000
#define NE 600000

// ---------- converts ----------
__global__ void cvt_f32_bf16(const float* __restrict__ in, bf16_t* __restrict__ out, int n4) {
    int t = blockIdx.x * blockDim.x + threadIdx.x;
    if (t >= n4) return;
    float4 v = ((const float4*)in)[t];
    bf16x4 o; o[0] = (bf16_t)v.x; o[1] = (bf16_t)v.y; o[2] = (bf16_t)v.z; o[3] = (bf16_t)v.w;
    ((bf16x4*)out)[t] = o;
}

// 47x256 fp32 -> 48x256 bf16 (zero-padded row 47)
__global__ void cvt_pad_w3(const float* __restrict__ in, bf16_t* __restrict__ out) {
    int t = blockIdx.x * blockDim.x + threadIdx.x;  // 48*64 = 3072 threads
    if (t >= 48 * 64) return;
    int row = t >> 6;
    int c4 = (t & 63) * 4;
    bf16x4 o;
    if (row < 47) {
        float4 v = *(const float4*)(in + row * 256 + c4);
        o[0] = (bf16_t)v.x; o[1] = (bf16_t)v.y; o[2] = (bf16_t)v.z; o[3] = (bf16_t)v.w;
    } else {
        o[0] = o[1] = o[2] = o[3] = (bf16_t)0.f;
    }
    *(bf16x4*)(out + row * 256 + c4) = o;
}

// ---------- degree ----------
__global__ void deg_kernel(const int* __restrict__ ei, float* __restrict__ deg, int E) {
    int e = blockIdx.x * blockDim.x + threadIdx.x;
    if (e < E) atomicAdd(&deg[ei[E + e]], 1.0f);
}

__global__ void deginv_kernel(float* __restrict__ deg, int n) {
    int i = blockIdx.x * blockDim.x + threadIdx.x;
    if (i < n) deg[i] = 1.0f / fmaxf(deg[i], 1.0f);
}

// ---------- scatters (mean-agg numerators, fp32 atomics) ----------
// C=128, fp32 source. 32 threads/edge, float4 each.
__global__ void scatter_f32_128(const int* __restrict__ ei, const float* __restrict__ X,
                                float* __restrict__ agg, int E) {
    int t = blockIdx.x * blockDim.x + threadIdx.x;
    int e = t >> 5;
    if (e >= E) return;
    int c = (t & 31) * 4;
    int s = ei[e], d = ei[E + e];
    float4 v = *(const float4*)(X + (long)s * 128 + c);
    float* p = agg + (long)d * 128 + c;
    atomicAdd(p + 0, v.x); atomicAdd(p + 1, v.y);
    atomicAdd(p + 2, v.z); atomicAdd(p + 3, v.w);
}

// C=256, bf16 source. 32 threads/edge, 8 elems each.
__global__ void scatter_bf16_256(const int* __restrict__ ei, const bf16_t* __restrict__ H,
                                 float* __restrict__ agg, int E) {
    int t = blockIdx.x * blockDim.x + threadIdx.x;
    int e = t >> 5;
    if (e >= E) return;
    int c = (t & 31) * 8;
    int s = ei[e], d = ei[E + e];
    bf16x8 v = *(const bf16x8*)(H + (long)s * 256 + c);
    float* p = agg + (long)d * 256 + c;
#pragma unroll
    for (int i = 0; i < 8; i++) atomicAdd(p + i, (float)v[i]);
}

// C=48, fp32 source (layer-3 post-matmul aggregation). 12 threads/edge.
__global__ void scatter_f32_48(const int* __restrict__ ei, const float* __restrict__ T,
                               float* __restrict__ agg, int E) {
    int t = blockIdx.x * blockDim.x + threadIdx.x;
    int e = t / 12;
    if (e >= E) return;
    int c = (t - e * 12) * 4;
    int s = ei[e], d = ei[E + e];
    float4 v = *(const float4*)(T + (long)s * 48 + c);
    float* p = agg + (long)d * 48 + c;
    atomicAdd(p + 0, v.x); atomicAdd(p + 1, v.y);
    atomicAdd(p + 2, v.z); atomicAdd(p + 3, v.w);
}

// ---------- scale by deg_inv and cvt to bf16 ----------
// CSH: threads-per-row = C/4 = 1<<CSH  (C=128 -> 5, C=256 -> 6)
template <int CSH>
__global__ void scale_bf16(const float* __restrict__ agg, const float* __restrict__ dinv,
                           bf16_t* __restrict__ out, int n4) {
    int t = blockIdx.x * blockDim.x + threadIdx.x;
    if (t >= n4) return;
    int row = t >> CSH;
    float di = dinv[row];
    float4 v = ((const float4*)agg)[t];
    bf16x4 o;
    o[0] = (bf16_t)(v.x * di); o[1] = (bf16_t)(v.y * di);
    o[2] = (bf16_t)(v.z * di); o[3] = (bf16_t)(v.w * di);
    ((bf16x4*)out)[t] = o;
}

// ---------- MFMA GEMM ----------
// Out[n, o] = act( sum_k A1[n,k]*W1[o,k]  (+ sum_k A2[n,k]*W2[o,k]) )
// One wave computes 64 rows x (16*CF) cols. NOUT must be divisible by 16*CF.
// mfma_f32_16x16x32_bf16 layouts (HW-verified m89/m91):
//   A-frag: lane holds A[m=lane&15][k=(lane>>4)*8 + j], j=0..7  -> 16B row-major load
//   B-frag: lane holds B[k=(lane>>4)*8+j][n=lane&15] = W[n][k]  -> 16B row-major load of W
//   C/D:    reg i -> row=(lane>>4)*4+i, col=lane&15
template <int CF, bool DUAL, bool RELU, bool OUT_BF16>
__global__ __launch_bounds__(256) void gemm_mfma(
    const bf16_t* __restrict__ A1, const bf16_t* __restrict__ A2,
    const bf16_t* __restrict__ W1, const bf16_t* __restrict__ W2,
    void* __restrict__ Out, int N, int K, int NOUT) {
    const int G = NOUT / (16 * CF);
    int lane = threadIdx.x & 63;
    int wid = blockIdx.x * 4 + (threadIdx.x >> 6);
    int rowTile = wid / G;
    int cg = wid - rowTile * G;
    int rowBase = rowTile * 64;
    if (rowBase >= N) return;
    int colBase = cg * 16 * CF;
    int m = lane & 15;
    int kq = (lane >> 4) * 8;

    f32x4 acc[4][CF];
#pragma unroll
    for (int a = 0; a < 4; a++)
#pragma unroll
        for (int b = 0; b < CF; b++) acc[a][b] = (f32x4){0.f, 0.f, 0.f, 0.f};

    long ar[4];
#pragma unroll
    for (int rf = 0; rf < 4; rf++) {
        int r = rowBase + rf * 16 + m;
        ar[rf] = (long)min(r, N - 1) * K;
    }

    for (int k0 = kq; k0 < K; k0 += 32) {
        bf16x8 a[4], b[CF];
#pragma unroll
        for (int rf = 0; rf < 4; rf++) a[rf] = *(const bf16x8*)(A1 + ar[rf] + k0);
#pragma unroll
        for (int cf = 0; cf < CF; cf++)
            b[cf] = *(const bf16x8*)(W1 + (long)(colBase + cf * 16 + m) * K + k0);
#pragma unroll
        for (int rf = 0; rf < 4; rf++)
#pragma unroll
            for (int cf = 0; cf < CF; cf++)
                acc[rf][cf] = __builtin_amdgcn_mfma_f32_16x16x32_bf16(a[rf], b[cf], acc[rf][cf], 0, 0, 0);
    }
    if constexpr (DUAL) {
        for (int k0 = kq; k0 < K; k0 += 32) {
            bf16x8 a[4], b[CF];
#pragma unroll
            for (int rf = 0; rf < 4; rf++) a[rf] = *(const bf16x8*)(A2 + ar[rf] + k0);
#pragma unroll
            for (int cf = 0; cf < CF; cf++)
                b[cf] = *(const bf16x8*)(W2 + (long)(colBase + cf * 16 + m) * K + k0);
#pragma unroll
            for (int rf = 0; rf < 4; rf++)
#pragma unroll
                for (int cf = 0; cf < CF; cf++)
                    acc[rf][cf] = __builtin_amdgcn_mfma_f32_16x16x32_bf16(a[rf], b[cf], acc[rf][cf], 0, 0, 0);
        }
    }

    int r0 = (lane >> 4) * 4;
#pragma unroll
    for (int rf = 0; rf < 4; rf++) {
#pragma unroll
        for (int i = 0; i < 4; i++) {
            int row = rowBase + rf * 16 + r0 + i;
            if (row >= N) continue;
#pragma unroll
            for (int cf = 0; cf < CF; cf++) {
                float v = acc[rf][cf][i];
                if (RELU) v = fmaxf(v, 0.f);
                int col = colBase + cf * 16 + m;
                if (OUT_BF16)
                    ((bf16_t*)Out)[(long)row * NOUT + col] = (bf16_t)v;
                else
                    ((float*)Out)[(long)row * NOUT + col] = v;
            }
        }
    }
}

// ---------- final: out = log_softmax(AGG3*dinv + R3) over 47 cols, 1 wave/row ----------
__global__ void final_kernel(const float* __restrict__ AGG3, const float* __restrict__ R3,
                             const float* __restrict__ dinv, float* __restrict__ out, int N) {
    int wid = blockIdx.x * (blockDim.x >> 6) + (threadIdx.x >> 6);
    int lane = threadIdx.x & 63;
    if (wid >= N) return;
    bool act = lane < 47;
    float di = dinv[wid];
    float v = act ? AGG3[(long)wid * 48 + lane] * di + R3[(long)wid * 48 + lane] : -INFINITY;
    float mx = v;
#pragma unroll
    for (int o = 32; o; o >>= 1) mx = fmaxf(mx, __shfl_xor(mx, o));
    float ex = act ? expf(v - mx) : 0.f;
    float s = ex;
#pragma unroll
    for (int o = 32; o; o >>= 1) s += __shfl_xor(s, o);
    float ls = logf(s);
    if (act) out[(long)wid * 47 + lane] = v - mx - ls;
}

extern "C" void kernel_launch(void* const* d_in, const int* in_sizes, int n_in,
                              void* d_out, int out_size, void* d_ws, size_t ws_size,
                              hipStream_t stream) {
    const float* x   = (const float*)d_in[0];
    const float* Wl1 = (const float*)d_in[1];
    const float* Wr1 = (const float*)d_in[2];
    const float* Wl2 = (const float*)d_in[3];
    const float* Wr2 = (const float*)d_in[4];
    const float* Wl3 = (const float*)d_in[5];
    const float* Wr3 = (const float*)d_in[6];
    const int*   ei  = (const int*)d_in[7];
    float* out = (float*)d_out;
    const int N = NN, E = NE;

    // workspace carve-up (256B aligned)
    char* ws = (char*)d_ws;
    size_t off = 0;
    auto carve = [&](size_t bytes) { void* p = ws + off; off = (off + bytes + 255) & ~(size_t)255; return p; };
    float*  deg  = (float*)carve((size_t)N * 4);             // becomes deg_inv in place
    float*  aggF = (float*)carve((size_t)N * 256 * 4);       // fp32 scatter accumulator
    bf16_t* aggB = (bf16_t*)carve((size_t)N * 256 * 2);      // scaled bf16 agg
    bf16_t* xB   = (bf16_t*)carve((size_t)N * 128 * 2);
    bf16_t* H1   = (bf16_t*)carve((size_t)N * 256 * 2);
    bf16_t* H2   = (bf16_t*)carve((size_t)N * 256 * 2);
    bf16_t* wb1l = (bf16_t*)carve(256 * 128 * 2);
    bf16_t* wb1r = (bf16_t*)carve(256 * 128 * 2);
    bf16_t* wb2l = (bf16_t*)carve(256 * 256 * 2);
    bf16_t* wb2r = (bf16_t*)carve(256 * 256 * 2);
    bf16_t* wb3l = (bf16_t*)carve(48 * 256 * 2);
    bf16_t* wb3r = (bf16_t*)carve(48 * 256 * 2);
    // layer-3 fp32 buffers reuse aggF region (free by then): stride 48
    float* T3   = aggF;
    float* AGG3 = aggF + (size_t)N * 48;
    float* R3   = aggF + (size_t)N * 96;

    // --- converts ---
    cvt_f32_bf16<<<(N * 32 + 255) / 256, 256, 0, stream>>>(x, xB, N * 32);
    cvt_f32_bf16<<<32, 256, 0, stream>>>(Wl1, wb1l, 256 * 32);
    cvt_f32_bf16<<<32, 256, 0, stream>>>(Wr1, wb1r, 256 * 32);
    cvt_f32_bf16<<<64, 256, 0, stream>>>(Wl2, wb2l, 256 * 64);
    cvt_f32_bf16<<<64, 256, 0, stream>>>(Wr2, wb2r, 256 * 64);
    cvt_pad_w3<<<12, 256, 0, stream>>>(Wl3, wb3l);
    cvt_pad_w3<<<12, 256, 0, stream>>>(Wr3, wb3r);

    // --- degrees ---
    hipMemsetAsync(deg, 0, (size_t)N * 4, stream);
    deg_kernel<<<(E + 255) / 256, 256, 0, stream>>>(ei, deg, E);
    deginv_kernel<<<(N + 255) / 256, 256, 0, stream>>>(deg, N);

    // --- layer 1 ---
    hipMemsetAsync(aggF, 0, (size_t)N * 128 * 4, stream);
    scatter_f32_128<<<(E * 32 + 255) / 256, 256, 0, stream>>>(ei, x, aggF, E);
    scale_bf16<5><<<(N * 32 + 255) / 256, 256, 0, stream>>>(aggF, deg, aggB, N * 32);
    gemm_mfma<4, true, true, true><<<782, 256, 0, stream>>>(aggB, xB, wb1l, wb1r, H1, N, 128, 256);

    // --- layer 2 ---
    hipMemsetAsync(aggF, 0, (size_t)N * 256 * 4, stream);
    scatter_bf16_256<<<(E * 32 + 255) / 256, 256, 0, stream>>>(ei, H1, aggF, E);
    scale_bf16<6><<<(N * 64 + 255) / 256, 256, 0, stream>>>(aggF, deg, aggB, N * 64);
    gemm_mfma<4, true, true, true><<<782, 256, 0, stream>>>(aggB, H1, wb2l, wb2r, H2, N, 256, 256);

    // --- layer 3 (matmul first, aggregate at 47 dims: agg(h2) @ W^T == agg(h2 @ W^T)) ---
    gemm_mfma<3, false, false, false><<<196, 256, 0, stream>>>(H2, (const bf16_t*)nullptr, wb3l,
                                                               (const bf16_t*)nullptr, T3, N, 256, 48);
    gemm_mfma<3, false, false, false><<<196, 256, 0, stream>>>(H2, (const bf16_t*)nullptr, wb3r,
                                                               (const bf16_t*)nullptr, R3, N, 256, 48);
    hipMemsetAsync(AGG3, 0, (size_t)N * 48 * 4, stream);
    scatter_f32_48<<<(E * 12 + 255) / 256, 256, 0, stream>>>(ei, T3, AGG3, E);

    // --- log_softmax ---
    final_kernel<<<(N + 3) / 4, 256, 0, stream>>>(AGG3, R3, deg, out, N);
}

// Round 2
// 494.466 us; speedup vs baseline: 11.7970x; 11.7970x over previous
//
#include <hip/hip_runtime.h>
#include <hip/hip_bf16.h>

typedef __bf16 bf16_t;
typedef __bf16 bf16x8 __attribute__((ext_vector_type(8)));
typedef __bf16 bf16x4 __attribute__((ext_vector_type(4)));
typedef __bf16 bf16x2 __attribute__((ext_vector_type(2)));
typedef float f32x4 __attribute__((ext_vector_type(4)));

#define NN 50000
#define NE 600000

// ---------- converts ----------
__global__ void cvt_f32_bf16(const float* __restrict__ in, bf16_t* __restrict__ out, int n4) {
    int t = blockIdx.x * blockDim.x + threadIdx.x;
    if (t >= n4) return;
    float4 v = ((const float4*)in)[t];
    bf16x4 o; o[0] = (bf16_t)v.x; o[1] = (bf16_t)v.y; o[2] = (bf16_t)v.z; o[3] = (bf16_t)v.w;
    ((bf16x4*)out)[t] = o;
}

// 47x256 fp32 -> 48x256 bf16 (zero-padded row 47)
__global__ void cvt_pad_w3(const float* __restrict__ in, bf16_t* __restrict__ out) {
    int t = blockIdx.x * blockDim.x + threadIdx.x;  // 48*64 = 3072 threads
    if (t >= 48 * 64) return;
    int row = t >> 6;
    int c4 = (t & 63) * 4;
    bf16x4 o;
    if (row < 47) {
        float4 v = *(const float4*)(in + row * 256 + c4);
        o[0] = (bf16_t)v.x; o[1] = (bf16_t)v.y; o[2] = (bf16_t)v.z; o[3] = (bf16_t)v.w;
    } else {
        o[0] = o[1] = o[2] = o[3] = (bf16_t)0.f;
    }
    *(bf16x4*)(out + row * 256 + c4) = o;
}

// ---------- CSR build ----------
__global__ void deg_count(const int* __restrict__ ei, int* __restrict__ degi, int E) {
    int e = blockIdx.x * blockDim.x + threadIdx.x;
    if (e < E) atomicAdd(&degi[ei[E + e]], 1);
}

// single-block inclusive-scan -> exclusive rowptr + dinv. 1024 threads.
__global__ void scan_kernel(const int* __restrict__ degi, int* __restrict__ rowptr,
                            float* __restrict__ dinv, int n) {
    __shared__ int smem[1024];
    __shared__ int carry_s;
    if (threadIdx.x == 0) carry_s = 0;
    __syncthreads();
    for (int base = 0; base < n; base += 1024) {
        int i = base + threadIdx.x;
        int v = (i < n) ? degi[i] : 0;
        smem[threadIdx.x] = v;
        __syncthreads();
#pragma unroll
        for (int off = 1; off < 1024; off <<= 1) {
            int t = (threadIdx.x >= off) ? smem[threadIdx.x - off] : 0;
            __syncthreads();
            smem[threadIdx.x] += t;
            __syncthreads();
        }
        int carry = carry_s;
        if (i < n) {
            rowptr[i] = carry + smem[threadIdx.x] - v;
            dinv[i] = 1.0f / fmaxf((float)v, 1.0f);
        }
        __syncthreads();
        if (threadIdx.x == 1023) carry_s = carry + smem[1023];
        __syncthreads();
    }
    if (threadIdx.x == 0) rowptr[n] = carry_s;
}

__global__ void copy_i32(const int* __restrict__ in, int* __restrict__ out, int n) {
    int i = blockIdx.x * blockDim.x + threadIdx.x;
    if (i < n) out[i] = in[i];
}

__global__ void fill_csr(const int* __restrict__ ei, int* __restrict__ cursor,
                         int* __restrict__ csr_src, int E) {
    int e = blockIdx.x * blockDim.x + threadIdx.x;
    if (e >= E) return;
    int d = ei[E + e];
    int pos = atomicAdd(&cursor[d], 1);
    csr_src[pos] = ei[e];
}

// ---------- gather aggregations (one wave per dst node) ----------
// C=128 fp32 source -> bf16 out (dinv fused). lane handles 2 cols (8B).
__global__ void gather_agg_128(const int* __restrict__ rowptr, const int* __restrict__ csr_src,
                               const float* __restrict__ X, const float* __restrict__ dinv,
                               bf16_t* __restrict__ out, int N) {
    int wid = blockIdx.x * (blockDim.x >> 6) + (threadIdx.x >> 6);
    if (wid >= N) return;
    int lane = threadIdx.x & 63;
    int c = lane * 2;
    int s0 = rowptr[wid], s1 = rowptr[wid + 1];
    float a0 = 0.f, a1 = 0.f, b0 = 0.f, b1 = 0.f;
    int j = s0;
    for (; j + 3 < s1; j += 4) {
        int sa = csr_src[j], sb = csr_src[j + 1], sc = csr_src[j + 2], sd = csr_src[j + 3];
        float2 va = *(const float2*)(X + (long)sa * 128 + c);
        float2 vb = *(const float2*)(X + (long)sb * 128 + c);
        float2 vc = *(const float2*)(X + (long)sc * 128 + c);
        float2 vd = *(const float2*)(X + (long)sd * 128 + c);
        a0 += va.x + vb.x; a1 += va.y + vb.y;
        b0 += vc.x + vd.x; b1 += vc.y + vd.y;
    }
    for (; j < s1; j++) {
        int sa = csr_src[j];
        float2 va = *(const float2*)(X + (long)sa * 128 + c);
        a0 += va.x; a1 += va.y;
    }
    float di = dinv[wid];
    bf16x2 o; o[0] = (bf16_t)((a0 + b0) * di); o[1] = (bf16_t)((a1 + b1) * di);
    *(bf16x2*)(out + (long)wid * 128 + c) = o;
}

// C=256 bf16 source -> bf16 out (fp32 accum, dinv fused). lane handles 4 cols (8B).
__global__ void gather_agg_256(const int* __restrict__ rowptr, const int* __restrict__ csr_src,
                               const bf16_t* __restrict__ H, const float* __restrict__ dinv,
                               bf16_t* __restrict__ out, int N) {
    int wid = blockIdx.x * (blockDim.x >> 6) + (threadIdx.x >> 6);
    if (wid >= N) return;
    int lane = threadIdx.x & 63;
    int c = lane * 4;
    int s0 = rowptr[wid], s1 = rowptr[wid + 1];
    float acc[4] = {0.f, 0.f, 0.f, 0.f};
    int j = s0;
    for (; j + 3 < s1; j += 4) {
        int sa = csr_src[j], sb = csr_src[j + 1], sc = csr_src[j + 2], sd = csr_src[j + 3];
        bf16x4 va = *(const bf16x4*)(H + (long)sa * 256 + c);
        bf16x4 vb = *(const bf16x4*)(H + (long)sb * 256 + c);
        bf16x4 vc = *(const bf16x4*)(H + (long)sc * 256 + c);
        bf16x4 vd = *(const bf16x4*)(H + (long)sd * 256 + c);
#pragma unroll
        for (int i = 0; i < 4; i++)
            acc[i] += (float)va[i] + (float)vb[i] + (float)vc[i] + (float)vd[i];
    }
    for (; j < s1; j++) {
        int sa = csr_src[j];
        bf16x4 va = *(const bf16x4*)(H + (long)sa * 256 + c);
#pragma unroll
        for (int i = 0; i < 4; i++) acc[i] += (float)va[i];
    }
    float di = dinv[wid];
    bf16x4 o;
#pragma unroll
    for (int i = 0; i < 4; i++) o[i] = (bf16_t)(acc[i] * di);
    *(bf16x4*)(out + (long)wid * 256 + c) = o;
}

// ---------- MFMA GEMM (unchanged from round 0) ----------
template <int CF, bool DUAL, bool RELU, bool OUT_BF16>
__global__ __launch_bounds__(256) void gemm_mfma(
    const bf16_t* __restrict__ A1, const bf16_t* __restrict__ A2,
    const bf16_t* __restrict__ W1, const bf16_t* __restrict__ W2,
    void* __restrict__ Out, int N, int K, int NOUT) {
    const int G = NOUT / (16 * CF);
    int lane = threadIdx.x & 63;
    int wid = blockIdx.x * 4 + (threadIdx.x >> 6);
    int rowTile = wid / G;
    int cg = wid - rowTile * G;
    int rowBase = rowTile * 64;
    if (rowBase >= N) return;
    int colBase = cg * 16 * CF;
    int m = lane & 15;
    int kq = (lane >> 4) * 8;

    f32x4 acc[4][CF];
#pragma unroll
    for (int a = 0; a < 4; a++)
#pragma unroll
        for (int b = 0; b < CF; b++) acc[a][b] = (f32x4){0.f, 0.f, 0.f, 0.f};

    long ar[4];
#pragma unroll
    for (int rf = 0; rf < 4; rf++) {
        int r = rowBase + rf * 16 + m;
        ar[rf] = (long)min(r, N - 1) * K;
    }

    for (int k0 = kq; k0 < K; k0 += 32) {
        bf16x8 a[4], b[CF];
#pragma unroll
        for (int rf = 0; rf < 4; rf++) a[rf] = *(const bf16x8*)(A1 + ar[rf] + k0);
#pragma unroll
        for (int cf = 0; cf < CF; cf++)
            b[cf] = *(const bf16x8*)(W1 + (long)(colBase + cf * 16 + m) * K + k0);
#pragma unroll
        for (int rf = 0; rf < 4; rf++)
#pragma unroll
            for (int cf = 0; cf < CF; cf++)
                acc[rf][cf] = __builtin_amdgcn_mfma_f32_16x16x32_bf16(a[rf], b[cf], acc[rf][cf], 0, 0, 0);
    }
    if constexpr (DUAL) {
        for (int k0 = kq; k0 < K; k0 += 32) {
            bf16x8 a[4], b[CF];
#pragma unroll
            for (int rf = 0; rf < 4; rf++) a[rf] = *(const bf16x8*)(A2 + ar[rf] + k0);
#pragma unroll
            for (int cf = 0; cf < CF; cf++)
                b[cf] = *(const bf16x8*)(W2 + (long)(colBase + cf * 16 + m) * K + k0);
#pragma unroll
            for (int rf = 0; rf < 4; rf++)
#pragma unroll
                for (int cf = 0; cf < CF; cf++)
                    acc[rf][cf] = __builtin_amdgcn_mfma_f32_16x16x32_bf16(a[rf], b[cf], acc[rf][cf], 0, 0, 0);
        }
    }

    int r0 = (lane >> 4) * 4;
#pragma unroll
    for (int rf = 0; rf < 4; rf++) {
#pragma unroll
        for (int i = 0; i < 4; i++) {
            int row = rowBase + rf * 16 + r0 + i;
            if (row >= N) continue;
#pragma unroll
            for (int cf = 0; cf < CF; cf++) {
                float v = acc[rf][cf][i];
                if (RELU) v = fmaxf(v, 0.f);
                int col = colBase + cf * 16 + m;
                if (OUT_BF16)
                    ((bf16_t*)Out)[(long)row * NOUT + col] = (bf16_t)v;
                else
                    ((float*)Out)[(long)row * NOUT + col] = v;
            }
        }
    }
}

// ---------- final: gather-agg T3 (48 cols) + dinv + R3 + log_softmax, 1 wave/row ----------
__global__ void final_fused(const int* __restrict__ rowptr, const int* __restrict__ csr_src,
                            const float* __restrict__ T3, const float* __restrict__ R3,
                            const float* __restrict__ dinv, float* __restrict__ out, int N) {
    int wid = blockIdx.x * (blockDim.x >> 6) + (threadIdx.x >> 6);
    int lane = threadIdx.x & 63;
    if (wid >= N) return;
    int s0 = rowptr[wid], s1 = rowptr[wid + 1];
    float a = 0.f, b = 0.f;
    if (lane < 48) {
        int j = s0;
        for (; j + 3 < s1; j += 4) {
            int sa = csr_src[j], sb = csr_src[j + 1], sc = csr_src[j + 2], sd = csr_src[j + 3];
            a += T3[(long)sa * 48 + lane] + T3[(long)sb * 48 + lane];
            b += T3[(long)sc * 48 + lane] + T3[(long)sd * 48 + lane];
        }
        for (; j < s1; j++) a += T3[(long)csr_src[j] * 48 + lane];
    }
    bool act = lane < 47;
    float v = act ? (a + b) * dinv[wid] + R3[(long)wid * 48 + lane] : -INFINITY;
    float mx = v;
#pragma unroll
    for (int o = 32; o; o >>= 1) mx = fmaxf(mx, __shfl_xor(mx, o));
    float ex = act ? expf(v - mx) : 0.f;
    float s = ex;
#pragma unroll
    for (int o = 32; o; o >>= 1) s += __shfl_xor(s, o);
    float ls = logf(s);
    if (act) out[(long)wid * 47 + lane] = v - mx - ls;
}

extern "C" void kernel_launch(void* const* d_in, const int* in_sizes, int n_in,
                              void* d_out, int out_size, void* d_ws, size_t ws_size,
                              hipStream_t stream) {
    const float* x   = (const float*)d_in[0];
    const float* Wl1 = (const float*)d_in[1];
    const float* Wr1 = (const float*)d_in[2];
    const float* Wl2 = (const float*)d_in[3];
    const float* Wr2 = (const float*)d_in[4];
    const float* Wl3 = (const float*)d_in[5];
    const float* Wr3 = (const float*)d_in[6];
    const int*   ei  = (const int*)d_in[7];
    float* out = (float*)d_out;
    const int N = NN, E = NE;

    char* ws = (char*)d_ws;
    size_t off = 0;
    auto carve = [&](size_t bytes) { void* p = ws + off; off = (off + bytes + 255) & ~(size_t)255; return p; };
    int*    degi    = (int*)carve((size_t)N * 4);
    int*    rowptr  = (int*)carve((size_t)(N + 1) * 4);
    int*    cursor  = (int*)carve((size_t)N * 4);
    int*    csr_src = (int*)carve((size_t)E * 4);
    float*  dinv    = (float*)carve((size_t)N * 4);
    bf16_t* aggB    = (bf16_t*)carve((size_t)N * 256 * 2);
    bf16_t* xB      = (bf16_t*)carve((size_t)N * 128 * 2);
    bf16_t* H1      = (bf16_t*)carve((size_t)N * 256 * 2);
    bf16_t* H2      = (bf16_t*)carve((size_t)N * 256 * 2);
    float*  T3      = (float*)carve((size_t)N * 48 * 4);
    float*  R3      = (float*)carve((size_t)N * 48 * 4);
    bf16_t* wb1l = (bf16_t*)carve(256 * 128 * 2);
    bf16_t* wb1r = (bf16_t*)carve(256 * 128 * 2);
    bf16_t* wb2l = (bf16_t*)carve(256 * 256 * 2);
    bf16_t* wb2r = (bf16_t*)carve(256 * 256 * 2);
    bf16_t* wb3l = (bf16_t*)carve(48 * 256 * 2);
    bf16_t* wb3r = (bf16_t*)carve(48 * 256 * 2);

    // --- converts (independent of CSR) ---
    cvt_f32_bf16<<<(N * 32 + 255) / 256, 256, 0, stream>>>(x, xB, N * 32);
    cvt_f32_bf16<<<32, 256, 0, stream>>>(Wl1, wb1l, 256 * 32);
    cvt_f32_bf16<<<32, 256, 0, stream>>>(Wr1, wb1r, 256 * 32);
    cvt_f32_bf16<<<64, 256, 0, stream>>>(Wl2, wb2l, 256 * 64);
    cvt_f32_bf16<<<64, 256, 0, stream>>>(Wr2, wb2r, 256 * 64);
    cvt_pad_w3<<<12, 256, 0, stream>>>(Wl3, wb3l);
    cvt_pad_w3<<<12, 256, 0, stream>>>(Wr3, wb3r);

    // --- CSR build ---
    hipMemsetAsync(degi, 0, (size_t)N * 4, stream);
    deg_count<<<(E + 255) / 256, 256, 0, stream>>>(ei, degi, E);
    scan_kernel<<<1, 1024, 0, stream>>>(degi, rowptr, dinv, N);
    copy_i32<<<(N + 255) / 256, 256, 0, stream>>>(rowptr, cursor, N);
    fill_csr<<<(E + 255) / 256, 256, 0, stream>>>(ei, cursor, csr_src, E);

    // --- layer 1: gather-agg(x) -> bf16 ; dual GEMM + relu -> H1 ---
    gather_agg_128<<<(N + 3) / 4, 256, 0, stream>>>(rowptr, csr_src, x, dinv, aggB, N);
    gemm_mfma<4, true, true, true><<<782, 256, 0, stream>>>(aggB, xB, wb1l, wb1r, H1, N, 128, 256);

    // --- layer 2 ---
    gather_agg_256<<<(N + 3) / 4, 256, 0, stream>>>(rowptr, csr_src, H1, dinv, aggB, N);
    gemm_mfma<4, true, true, true><<<782, 256, 0, stream>>>(aggB, H1, wb2l, wb2r, H2, N, 256, 256);

    // --- layer 3: matmuls first (agg is linear), then fused gather+log_softmax ---
    gemm_mfma<3, false, false, false><<<196, 256, 0, stream>>>(H2, (const bf16_t*)nullptr, wb3l,
                                                               (const bf16_t*)nullptr, T3, N, 256, 48);
    gemm_mfma<3, false, false, false><<<196, 256, 0, stream>>>(H2, (const bf16_t*)nullptr, wb3r,
                                                               (const bf16_t*)nullptr, R3, N, 256, 48);
    final_fused<<<(N + 3) / 4, 256, 0, stream>>>(rowptr, csr_src, T3, R3, dinv, out, N);
}

// Round 3
// 410.145 us; speedup vs baseline: 14.2224x; 1.2056x over previous
//
#include <hip/hip_runtime.h>
#include <hip/hip_bf16.h>

typedef __bf16 bf16_t;
typedef __bf16 bf16x8 __attribute__((ext_vector_type(8)));
typedef __bf16 bf16x4 __attribute__((ext_vector_type(4)));
typedef __bf16 bf16x2 __attribute__((ext_vector_type(2)));
typedef float f32x4 __attribute__((ext_vector_type(4)));

#define NN 50000
#define NE 600000

// ---------- converts ----------
__global__ void cvt_f32_bf16(const float* __restrict__ in, bf16_t* __restrict__ out, int n4) {
    int t = blockIdx.x * blockDim.x + threadIdx.x;
    if (t >= n4) return;
    float4 v = ((const float4*)in)[t];
    bf16x4 o; o[0] = (bf16_t)v.x; o[1] = (bf16_t)v.y; o[2] = (bf16_t)v.z; o[3] = (bf16_t)v.w;
    ((bf16x4*)out)[t] = o;
}

// 47x256 fp32 -> 48x256 bf16 (zero-padded row 47)
__global__ void cvt_pad_w3(const float* __restrict__ in, bf16_t* __restrict__ out) {
    int t = blockIdx.x * blockDim.x + threadIdx.x;  // 48*64 = 3072 threads
    if (t >= 48 * 64) return;
    int row = t >> 6;
    int c4 = (t & 63) * 4;
    bf16x4 o;
    if (row < 47) {
        float4 v = *(const float4*)(in + row * 256 + c4);
        o[0] = (bf16_t)v.x; o[1] = (bf16_t)v.y; o[2] = (bf16_t)v.z; o[3] = (bf16_t)v.w;
    } else {
        o[0] = o[1] = o[2] = o[3] = (bf16_t)0.f;
    }
    *(bf16x4*)(out + row * 256 + c4) = o;
}

// ---------- CSR build ----------
__global__ void deg_count(const int* __restrict__ ei, int* __restrict__ degi, int E) {
    int e = blockIdx.x * blockDim.x + threadIdx.x;
    if (e < E) atomicAdd(&degi[ei[E + e]], 1);
}

// phase 1: per-block (1024 elems) exclusive scan via wave shfl + LDS wave-sums.
__global__ __launch_bounds__(1024) void scan_blocks(const int* __restrict__ degi,
                                                    int* __restrict__ rowptr,
                                                    float* __restrict__ dinv,
                                                    int* __restrict__ partials, int n) {
    int i = blockIdx.x * 1024 + threadIdx.x;
    int v = (i < n) ? degi[i] : 0;
    int lane = threadIdx.x & 63;
    int w = threadIdx.x >> 6;
    int s = v;
#pragma unroll
    for (int o = 1; o < 64; o <<= 1) {
        int t = __shfl_up(s, o);
        if (lane >= o) s += t;
    }
    __shared__ int wsum[16];
    if (lane == 63) wsum[w] = s;
    __syncthreads();
    if (threadIdx.x < 16) {
        int t = wsum[threadIdx.x];
#pragma unroll
        for (int o = 1; o < 16; o <<= 1) {
            int u = __shfl_up(t, o);
            if ((int)threadIdx.x >= o) t += u;
        }
        wsum[threadIdx.x] = t;
    }
    __syncthreads();
    int incl = s + ((w > 0) ? wsum[w - 1] : 0);
    if (i < n) {
        rowptr[i] = incl - v;  // exclusive within block (carry added in phase 3)
        dinv[i] = 1.0f / fmaxf((float)v, 1.0f);
    }
    if (threadIdx.x == 1023) partials[blockIdx.x] = incl;
}

// phase 2: one wave scans block partials (nb <= 64), writes exclusive offsets + total.
__global__ void scan_partials(const int* __restrict__ partials, int* __restrict__ blockofs,
                              int* __restrict__ rowptr, int nb, int n) {
    int lane = threadIdx.x;
    int v = (lane < nb) ? partials[lane] : 0;
    int s = v;
#pragma unroll
    for (int o = 1; o < 64; o <<= 1) {
        int t = __shfl_up(s, o);
        if (lane >= o) s += t;
    }
    if (lane < nb) blockofs[lane] = s - v;
    if (lane == 63) rowptr[n] = s;
}

// phase 3: add block offsets; also write cursor copy for fill_csr.
__global__ void add_offsets(int* __restrict__ rowptr, int* __restrict__ cursor,
                            const int* __restrict__ blockofs, int n) {
    int i = blockIdx.x * blockDim.x + threadIdx.x;
    if (i >= n) return;
    int v = rowptr[i] + blockofs[i >> 10];
    rowptr[i] = v;
    cursor[i] = v;
}

__global__ void fill_csr(const int* __restrict__ ei, int* __restrict__ cursor,
                         int* __restrict__ csr_src, int E) {
    int e = blockIdx.x * blockDim.x + threadIdx.x;
    if (e >= E) return;
    int d = ei[E + e];
    int pos = atomicAdd(&cursor[d], 1);
    csr_src[pos] = ei[e];
}

// ---------- gather aggregations (one wave per dst node) ----------
// C=128 fp32 source -> bf16 out (dinv fused). lane handles 2 cols (8B).
__global__ void gather_agg_128(const int* __restrict__ rowptr, const int* __restrict__ csr_src,
                               const float* __restrict__ X, const float* __restrict__ dinv,
                               bf16_t* __restrict__ out, int N) {
    int wid = blockIdx.x * (blockDim.x >> 6) + (threadIdx.x >> 6);
    if (wid >= N) return;
    int lane = threadIdx.x & 63;
    int c = lane * 2;
    int s0 = rowptr[wid], s1 = rowptr[wid + 1];
    float a0 = 0.f, a1 = 0.f, b0 = 0.f, b1 = 0.f;
    int j = s0;
    for (; j + 3 < s1; j += 4) {
        int sa = csr_src[j], sb = csr_src[j + 1], sc = csr_src[j + 2], sd = csr_src[j + 3];
        float2 va = *(const float2*)(X + (long)sa * 128 + c);
        float2 vb = *(const float2*)(X + (long)sb * 128 + c);
        float2 vc = *(const float2*)(X + (long)sc * 128 + c);
        float2 vd = *(const float2*)(X + (long)sd * 128 + c);
        a0 += va.x + vb.x; a1 += va.y + vb.y;
        b0 += vc.x + vd.x; b1 += vc.y + vd.y;
    }
    for (; j < s1; j++) {
        int sa = csr_src[j];
        float2 va = *(const float2*)(X + (long)sa * 128 + c);
        a0 += va.x; a1 += va.y;
    }
    float di = dinv[wid];
    bf16x2 o; o[0] = (bf16_t)((a0 + b0) * di); o[1] = (bf16_t)((a1 + b1) * di);
    *(bf16x2*)(out + (long)wid * 128 + c) = o;
}

// C=256 bf16 source -> bf16 out (fp32 accum, dinv fused). lane handles 4 cols (8B).
__global__ void gather_agg_256(const int* __restrict__ rowptr, const int* __restrict__ csr_src,
                               const bf16_t* __restrict__ H, const float* __restrict__ dinv,
                               bf16_t* __restrict__ out, int N) {
    int wid = blockIdx.x * (blockDim.x >> 6) + (threadIdx.x >> 6);
    if (wid >= N) return;
    int lane = threadIdx.x & 63;
    int c = lane * 4;
    int s0 = rowptr[wid], s1 = rowptr[wid + 1];
    float acc[4] = {0.f, 0.f, 0.f, 0.f};
    int j = s0;
    for (; j + 3 < s1; j += 4) {
        int sa = csr_src[j], sb = csr_src[j + 1], sc = csr_src[j + 2], sd = csr_src[j + 3];
        bf16x4 va = *(const bf16x4*)(H + (long)sa * 256 + c);
        bf16x4 vb = *(const bf16x4*)(H + (long)sb * 256 + c);
        bf16x4 vc = *(const bf16x4*)(H + (long)sc * 256 + c);
        bf16x4 vd = *(const bf16x4*)(H + (long)sd * 256 + c);
#pragma unroll
        for (int i = 0; i < 4; i++)
            acc[i] += (float)va[i] + (float)vb[i] + (float)vc[i] + (float)vd[i];
    }
    for (; j < s1; j++) {
        int sa = csr_src[j];
        bf16x4 va = *(const bf16x4*)(H + (long)sa * 256 + c);
#pragma unroll
        for (int i = 0; i < 4; i++) acc[i] += (float)va[i];
    }
    float di = dinv[wid];
    bf16x4 o;
#pragma unroll
    for (int i = 0; i < 4; i++) o[i] = (bf16_t)(acc[i] * di);
    *(bf16x4*)(out + (long)wid * 256 + c) = o;
}

// ---------- MFMA GEMM ----------
template <int CF, bool DUAL, bool RELU, bool OUT_BF16>
__global__ __launch_bounds__(256) void gemm_mfma(
    const bf16_t* __restrict__ A1, const bf16_t* __restrict__ A2,
    const bf16_t* __restrict__ W1, const bf16_t* __restrict__ W2,
    void* __restrict__ Out, int N, int K, int NOUT) {
    const int G = NOUT / (16 * CF);
    int lane = threadIdx.x & 63;
    int wid = blockIdx.x * 4 + (threadIdx.x >> 6);
    int rowTile = wid / G;
    int cg = wid - rowTile * G;
    int rowBase = rowTile * 64;
    if (rowBase >= N) return;
    int colBase = cg * 16 * CF;
    int m = lane & 15;
    int kq = (lane >> 4) * 8;

    f32x4 acc[4][CF];
#pragma unroll
    for (int a = 0; a < 4; a++)
#pragma unroll
        for (int b = 0; b < CF; b++) acc[a][b] = (f32x4){0.f, 0.f, 0.f, 0.f};

    long ar[4];
#pragma unroll
    for (int rf = 0; rf < 4; rf++) {
        int r = rowBase + rf * 16 + m;
        ar[rf] = (long)min(r, N - 1) * K;
    }

    for (int k0 = kq; k0 < K; k0 += 32) {
        bf16x8 a[4], b[CF];
#pragma unroll
        for (int rf = 0; rf < 4; rf++) a[rf] = *(const bf16x8*)(A1 + ar[rf] + k0);
#pragma unroll
        for (int cf = 0; cf < CF; cf++)
            b[cf] = *(const bf16x8*)(W1 + (long)(colBase + cf * 16 + m) * K + k0);
#pragma unroll
        for (int rf = 0; rf < 4; rf++)
#pragma unroll
            for (int cf = 0; cf < CF; cf++)
                acc[rf][cf] = __builtin_amdgcn_mfma_f32_16x16x32_bf16(a[rf], b[cf], acc[rf][cf], 0, 0, 0);
    }
    if constexpr (DUAL) {
        for (int k0 = kq; k0 < K; k0 += 32) {
            bf16x8 a[4], b[CF];
#pragma unroll
            for (int rf = 0; rf < 4; rf++) a[rf] = *(const bf16x8*)(A2 + ar[rf] + k0);
#pragma unroll
            for (int cf = 0; cf < CF; cf++)
                b[cf] = *(const bf16x8*)(W2 + (long)(colBase + cf * 16 + m) * K + k0);
#pragma unroll
            for (int rf = 0; rf < 4; rf++)
#pragma unroll
                for (int cf = 0; cf < CF; cf++)
                    acc[rf][cf] = __builtin_amdgcn_mfma_f32_16x16x32_bf16(a[rf], b[cf], acc[rf][cf], 0, 0, 0);
        }
    }

    int r0 = (lane >> 4) * 4;
#pragma unroll
    for (int rf = 0; rf < 4; rf++) {
#pragma unroll
        for (int i = 0; i < 4; i++) {
            int row = rowBase + rf * 16 + r0 + i;
            if (row >= N) continue;
#pragma unroll
            for (int cf = 0; cf < CF; cf++) {
                float v = acc[rf][cf][i];
                if (RELU) v = fmaxf(v, 0.f);
                int col = colBase + cf * 16 + m;
                if (OUT_BF16)
                    ((bf16_t*)Out)[(long)row * NOUT + col] = (bf16_t)v;
                else
                    ((float*)Out)[(long)row * NOUT + col] = v;
            }
        }
    }
}

// ---------- final: gather-agg T3 (48 cols) + dinv + R3 + log_softmax, 1 wave/row ----------
__global__ void final_fused(const int* __restrict__ rowptr, const int* __restrict__ csr_src,
                            const float* __restrict__ T3, const float* __restrict__ R3,
                            const float* __restrict__ dinv, float* __restrict__ out, int N) {
    int wid = blockIdx.x * (blockDim.x >> 6) + (threadIdx.x >> 6);
    int lane = threadIdx.x & 63;
    if (wid >= N) return;
    int s0 = rowptr[wid], s1 = rowptr[wid + 1];
    float a = 0.f, b = 0.f;
    if (lane < 48) {
        int j = s0;
        for (; j + 3 < s1; j += 4) {
            int sa = csr_src[j], sb = csr_src[j + 1], sc = csr_src[j + 2], sd = csr_src[j + 3];
            a += T3[(long)sa * 48 + lane] + T3[(long)sb * 48 + lane];
            b += T3[(long)sc * 48 + lane] + T3[(long)sd * 48 + lane];
        }
        for (; j < s1; j++) a += T3[(long)csr_src[j] * 48 + lane];
    }
    bool act = lane < 47;
    float v = act ? (a + b) * dinv[wid] + R3[(long)wid * 48 + lane] : -INFINITY;
    float mx = v;
#pragma unroll
    for (int o = 32; o; o >>= 1) mx = fmaxf(mx, __shfl_xor(mx, o));
    float ex = act ? expf(v - mx) : 0.f;
    float s = ex;
#pragma unroll
    for (int o = 32; o; o >>= 1) s += __shfl_xor(s, o);
    float ls = logf(s);
    if (act) out[(long)wid * 47 + lane] = v - mx - ls;
}

extern "C" void kernel_launch(void* const* d_in, const int* in_sizes, int n_in,
                              void* d_out, int out_size, void* d_ws, size_t ws_size,
                              hipStream_t stream) {
    const float* x   = (const float*)d_in[0];
    const float* Wl1 = (const float*)d_in[1];
    const float* Wr1 = (const float*)d_in[2];
    const float* Wl2 = (const float*)d_in[3];
    const float* Wr2 = (const float*)d_in[4];
    const float* Wl3 = (const float*)d_in[5];
    const float* Wr3 = (const float*)d_in[6];
    const int*   ei  = (const int*)d_in[7];
    float* out = (float*)d_out;
    const int N = NN, E = NE;
    const int NB = (N + 1023) / 1024;  // 49

    char* ws = (char*)d_ws;
    size_t off = 0;
    auto carve = [&](size_t bytes) { void* p = ws + off; off = (off + bytes + 255) & ~(size_t)255; return p; };
    int*    degi     = (int*)carve((size_t)N * 4);
    int*    rowptr   = (int*)carve((size_t)(N + 1) * 4);
    int*    cursor   = (int*)carve((size_t)N * 4);
    int*    csr_src  = (int*)carve((size_t)E * 4);
    int*    partials = (int*)carve(64 * 4);
    int*    blockofs = (int*)carve(64 * 4);
    float*  dinv     = (float*)carve((size_t)N * 4);
    bf16_t* aggB     = (bf16_t*)carve((size_t)N * 256 * 2);
    bf16_t* xB       = (bf16_t*)carve((size_t)N * 128 * 2);
    bf16_t* H1       = (bf16_t*)carve((size_t)N * 256 * 2);
    bf16_t* H2       = (bf16_t*)carve((size_t)N * 256 * 2);
    float*  T3       = (float*)carve((size_t)N * 48 * 4);
    float*  R3       = (float*)carve((size_t)N * 48 * 4);
    bf16_t* wb1l = (bf16_t*)carve(256 * 128 * 2);
    bf16_t* wb1r = (bf16_t*)carve(256 * 128 * 2);
    bf16_t* wb2l = (bf16_t*)carve(256 * 256 * 2);
    bf16_t* wb2r = (bf16_t*)carve(256 * 256 * 2);
    bf16_t* wb3l = (bf16_t*)carve(48 * 256 * 2);
    bf16_t* wb3r = (bf16_t*)carve(48 * 256 * 2);

    // --- converts (independent of CSR) ---
    cvt_f32_bf16<<<(N * 32 + 255) / 256, 256, 0, stream>>>(x, xB, N * 32);
    cvt_f32_bf16<<<32, 256, 0, stream>>>(Wl1, wb1l, 256 * 32);
    cvt_f32_bf16<<<32, 256, 0, stream>>>(Wr1, wb1r, 256 * 32);
    cvt_f32_bf16<<<64, 256, 0, stream>>>(Wl2, wb2l, 256 * 64);
    cvt_f32_bf16<<<64, 256, 0, stream>>>(Wr2, wb2r, 256 * 64);
    cvt_pad_w3<<<12, 256, 0, stream>>>(Wl3, wb3l);
    cvt_pad_w3<<<12, 256, 0, stream>>>(Wr3, wb3r);

    // --- CSR build (hierarchical scan) ---
    hipMemsetAsync(degi, 0, (size_t)N * 4, stream);
    deg_count<<<(E + 255) / 256, 256, 0, stream>>>(ei, degi, E);
    scan_blocks<<<NB, 1024, 0, stream>>>(degi, rowptr, dinv, partials, N);
    scan_partials<<<1, 64, 0, stream>>>(partials, blockofs, rowptr, NB, N);
    add_offsets<<<(N + 255) / 256, 256, 0, stream>>>(rowptr, cursor, blockofs, N);
    fill_csr<<<(E + 255) / 256, 256, 0, stream>>>(ei, cursor, csr_src, E);

    // --- layer 1: gather-agg(x) -> bf16 ; dual GEMM + relu -> H1 ---
    gather_agg_128<<<(N + 3) / 4, 256, 0, stream>>>(rowptr, csr_src, x, dinv, aggB, N);
    gemm_mfma<4, true, true, true><<<782, 256, 0, stream>>>(aggB, xB, wb1l, wb1r, H1, N, 128, 256);

    // --- layer 2 ---
    gather_agg_256<<<(N + 3) / 4, 256, 0, stream>>>(rowptr, csr_src, H1, dinv, aggB, N);
    gemm_mfma<4, true, true, true><<<782, 256, 0, stream>>>(aggB, H1, wb2l, wb2r, H2, N, 256, 256);

    // --- layer 3: matmuls first (agg is linear), then fused gather+log_softmax ---
    gemm_mfma<3, false, false, false><<<196, 256, 0, stream>>>(H2, (const bf16_t*)nullptr, wb3l,
                                                               (const bf16_t*)nullptr, T3, N, 256, 48);
    gemm_mfma<3, false, false, false><<<196, 256, 0, stream>>>(H2, (const bf16_t*)nullptr, wb3r,
                                                               (const bf16_t*)nullptr, R3, N, 256, 48);
    final_fused<<<(N + 3) / 4, 256, 0, stream>>>(rowptr, csr_src, T3, R3, dinv, out, N);
}

// Round 4
// 357.631 us; speedup vs baseline: 16.3108x; 1.1468x over previous
//
#include <hip/hip_runtime.h>
#include <hip/hip_bf16.h>

typedef __bf16 bf16_t;
typedef __bf16 bf16x8 __attribute__((ext_vector_type(8)));
typedef __bf16 bf16x4 __attribute__((ext_vector_type(4)));
typedef __bf16 bf16x2 __attribute__((ext_vector_type(2)));
typedef float f32x4 __attribute__((ext_vector_type(4)));

#define NN 50000
#define NE 600000

__device__ __forceinline__ void gload_lds16(const void* g, void* l) {
    __builtin_amdgcn_global_load_lds(
        (const __attribute__((address_space(1))) void*)g,
        (__attribute__((address_space(3))) void*)l, 16, 0, 0);
}

// ---------- converts ----------
__global__ void cvt_f32_bf16(const float* __restrict__ in, bf16_t* __restrict__ out, int n4) {
    int t = blockIdx.x * blockDim.x + threadIdx.x;
    if (t >= n4) return;
    float4 v = ((const float4*)in)[t];
    bf16x4 o; o[0] = (bf16_t)v.x; o[1] = (bf16_t)v.y; o[2] = (bf16_t)v.z; o[3] = (bf16_t)v.w;
    ((bf16x4*)out)[t] = o;
}

// 47x256 fp32 -> 48x256 bf16 (zero-padded row 47)
__global__ void cvt_pad_w3(const float* __restrict__ in, bf16_t* __restrict__ out) {
    int t = blockIdx.x * blockDim.x + threadIdx.x;
    if (t >= 48 * 64) return;
    int row = t >> 6;
    int c4 = (t & 63) * 4;
    bf16x4 o;
    if (row < 47) {
        float4 v = *(const float4*)(in + row * 256 + c4);
        o[0] = (bf16_t)v.x; o[1] = (bf16_t)v.y; o[2] = (bf16_t)v.z; o[3] = (bf16_t)v.w;
    } else {
        o[0] = o[1] = o[2] = o[3] = (bf16_t)0.f;
    }
    *(bf16x4*)(out + row * 256 + c4) = o;
}

// ---------- CSR build ----------
__global__ void deg_count(const int* __restrict__ ei, int* __restrict__ degi, int E) {
    int e = blockIdx.x * blockDim.x + threadIdx.x;
    if (e < E) atomicAdd(&degi[ei[E + e]], 1);
}

__global__ __launch_bounds__(1024) void scan_blocks(const int* __restrict__ degi,
                                                    int* __restrict__ rowptr,
                                                    float* __restrict__ dinv,
                                                    int* __restrict__ partials, int n) {
    int i = blockIdx.x * 1024 + threadIdx.x;
    int v = (i < n) ? degi[i] : 0;
    int lane = threadIdx.x & 63;
    int w = threadIdx.x >> 6;
    int s = v;
#pragma unroll
    for (int o = 1; o < 64; o <<= 1) {
        int t = __shfl_up(s, o);
        if (lane >= o) s += t;
    }
    __shared__ int wsum[16];
    if (lane == 63) wsum[w] = s;
    __syncthreads();
    if (threadIdx.x < 16) {
        int t = wsum[threadIdx.x];
#pragma unroll
        for (int o = 1; o < 16; o <<= 1) {
            int u = __shfl_up(t, o);
            if ((int)threadIdx.x >= o) t += u;
        }
        wsum[threadIdx.x] = t;
    }
    __syncthreads();
    int incl = s + ((w > 0) ? wsum[w - 1] : 0);
    if (i < n) {
        rowptr[i] = incl - v;
        dinv[i] = 1.0f / fmaxf((float)v, 1.0f);
    }
    if (threadIdx.x == 1023) partials[blockIdx.x] = incl;
}

__global__ void scan_partials(const int* __restrict__ partials, int* __restrict__ blockofs,
                              int* __restrict__ rowptr, int nb, int n) {
    int lane = threadIdx.x;
    int v = (lane < nb) ? partials[lane] : 0;
    int s = v;
#pragma unroll
    for (int o = 1; o < 64; o <<= 1) {
        int t = __shfl_up(s, o);
        if (lane >= o) s += t;
    }
    if (lane < nb) blockofs[lane] = s - v;
    if (lane == 63) rowptr[n] = s;
}

__global__ void add_offsets(int* __restrict__ rowptr, int* __restrict__ cursor,
                            const int* __restrict__ blockofs, int n) {
    int i = blockIdx.x * blockDim.x + threadIdx.x;
    if (i >= n) return;
    int v = rowptr[i] + blockofs[i >> 10];
    rowptr[i] = v;
    cursor[i] = v;
}

__global__ void fill_csr(const int* __restrict__ ei, int* __restrict__ cursor,
                         int* __restrict__ csr_src, int E) {
    int e = blockIdx.x * blockDim.x + threadIdx.x;
    if (e >= E) return;
    int d = ei[E + e];
    int pos = atomicAdd(&cursor[d], 1);
    csr_src[pos] = ei[e];
}

// ---------- gather aggregations (one wave per dst node) ----------
__global__ void gather_agg_128(const int* __restrict__ rowptr, const int* __restrict__ csr_src,
                               const float* __restrict__ X, const float* __restrict__ dinv,
                               bf16_t* __restrict__ out, int N) {
    int wid = blockIdx.x * (blockDim.x >> 6) + (threadIdx.x >> 6);
    if (wid >= N) return;
    int lane = threadIdx.x & 63;
    int c = lane * 2;
    int s0 = rowptr[wid], s1 = rowptr[wid + 1];
    float a0 = 0.f, a1 = 0.f, b0 = 0.f, b1 = 0.f;
    int j = s0;
    for (; j + 3 < s1; j += 4) {
        int sa = csr_src[j], sb = csr_src[j + 1], sc = csr_src[j + 2], sd = csr_src[j + 3];
        float2 va = *(const float2*)(X + (long)sa * 128 + c);
        float2 vb = *(const float2*)(X + (long)sb * 128 + c);
        float2 vc = *(const float2*)(X + (long)sc * 128 + c);
        float2 vd = *(const float2*)(X + (long)sd * 128 + c);
        a0 += va.x + vb.x; a1 += va.y + vb.y;
        b0 += vc.x + vd.x; b1 += vc.y + vd.y;
    }
    for (; j < s1; j++) {
        int sa = csr_src[j];
        float2 va = *(const float2*)(X + (long)sa * 128 + c);
        a0 += va.x; a1 += va.y;
    }
    float di = dinv[wid];
    bf16x2 o; o[0] = (bf16_t)((a0 + b0) * di); o[1] = (bf16_t)((a1 + b1) * di);
    *(bf16x2*)(out + (long)wid * 128 + c) = o;
}

__global__ void gather_agg_256(const int* __restrict__ rowptr, const int* __restrict__ csr_src,
                               const bf16_t* __restrict__ H, const float* __restrict__ dinv,
                               bf16_t* __restrict__ out, int N) {
    int wid = blockIdx.x * (blockDim.x >> 6) + (threadIdx.x >> 6);
    if (wid >= N) return;
    int lane = threadIdx.x & 63;
    int c = lane * 4;
    int s0 = rowptr[wid], s1 = rowptr[wid + 1];
    float acc[4] = {0.f, 0.f, 0.f, 0.f};
    int j = s0;
    for (; j + 3 < s1; j += 4) {
        int sa = csr_src[j], sb = csr_src[j + 1], sc = csr_src[j + 2], sd = csr_src[j + 3];
        bf16x4 va = *(const bf16x4*)(H + (long)sa * 256 + c);
        bf16x4 vb = *(const bf16x4*)(H + (long)sb * 256 + c);
        bf16x4 vc = *(const bf16x4*)(H + (long)sc * 256 + c);
        bf16x4 vd = *(const bf16x4*)(H + (long)sd * 256 + c);
#pragma unroll
        for (int i = 0; i < 4; i++)
            acc[i] += (float)va[i] + (float)vb[i] + (float)vc[i] + (float)vd[i];
    }
    for (; j < s1; j++) {
        int sa = csr_src[j];
        bf16x4 va = *(const bf16x4*)(H + (long)sa * 256 + c);
#pragma unroll
        for (int i = 0; i < 4; i++) acc[i] += (float)va[i];
    }
    float di = dinv[wid];
    bf16x4 o;
#pragma unroll
    for (int i = 0; i < 4; i++) o[i] = (bf16_t)(acc[i] * di);
    *(bf16x4*)(out + (long)wid * 256 + c) = o;
}

// ---------- LDS-staged MFMA GEMM: 128x128 tile / block, BK=64 slices ----------
// 4 waves in 2x2; global_load_lds width-16 staging with seg XOR swizzle so that
// ds_read_b128 fragment reads are bank-conflict-free (2-way = free minimum).
// LDS chunk c (16B) of a slice holds src(row=c>>3, seg=(c&7)^((c>>3)&7)).
template <int KTOT, bool DUAL, bool RELU>
__global__ __launch_bounds__(256) void gemm_lds(
    const bf16_t* __restrict__ A1, const bf16_t* __restrict__ A2,
    const bf16_t* __restrict__ W1, const bf16_t* __restrict__ W2,
    bf16_t* __restrict__ Out, int N, int NOUT) {
    __shared__ bf16_t As[128 * 64];
    __shared__ bf16_t Bs[128 * 64];
    int tid = threadIdx.x;
    int w = tid >> 6, lane = tid & 63;
    int wr = w >> 1, wc = w & 1;
    int rowBase = blockIdx.x * 128;
    int colBase = blockIdx.y * 128;
    int m = lane & 15, q = lane >> 4;

    // staging address precompute: 4 calls/thread per matrix per slice
    long aoff[4], boff[4];
    int ldsOff[4];  // in bf16 elems
#pragma unroll
    for (int i = 0; i < 4; i++) {
        int c = w * 256 + i * 64 + lane;
        int r = c >> 3, s = c & 7;
        int gk = (s ^ (r & 7)) << 3;
        aoff[i] = (long)min(rowBase + r, N - 1) * KTOT + gk;
        boff[i] = (long)(colBase + r) * KTOT + gk;
        ldsOff[i] = (w * 4 + i) * 512;
    }

    f32x4 acc[4][4];
#pragma unroll
    for (int a = 0; a < 4; a++)
#pragma unroll
        for (int b = 0; b < 4; b++) acc[a][b] = (f32x4){0.f, 0.f, 0.f, 0.f};

#pragma unroll
    for (int half = 0; half < (DUAL ? 2 : 1); half++) {
        const bf16_t* A = half ? A2 : A1;
        const bf16_t* W = half ? W2 : W1;
#pragma unroll
        for (int k0 = 0; k0 < KTOT; k0 += 64) {
            __syncthreads();  // previous slice's LDS reads done
#pragma unroll
            for (int i = 0; i < 4; i++) {
                gload_lds16(A + aoff[i] + k0, As + ldsOff[i]);
                gload_lds16(W + boff[i] + k0, Bs + ldsOff[i]);
            }
            __syncthreads();  // staging visible (compiler drains vmcnt)
#pragma unroll
            for (int ks = 0; ks < 2; ks++) {
                bf16x8 af[4], bfr[4];
#pragma unroll
                for (int rf = 0; rf < 4; rf++) {
                    int r = wr * 64 + rf * 16 + m;
                    int seg = ks * 4 + q;
                    af[rf] = *(const bf16x8*)(As + r * 64 + ((seg ^ (r & 7)) << 3));
                }
#pragma unroll
                for (int cf = 0; cf < 4; cf++) {
                    int r = wc * 64 + cf * 16 + m;
                    int seg = ks * 4 + q;
                    bfr[cf] = *(const bf16x8*)(Bs + r * 64 + ((seg ^ (r & 7)) << 3));
                }
#pragma unroll
                for (int rf = 0; rf < 4; rf++)
#pragma unroll
                    for (int cf = 0; cf < 4; cf++)
                        acc[rf][cf] = __builtin_amdgcn_mfma_f32_16x16x32_bf16(af[rf], bfr[cf], acc[rf][cf], 0, 0, 0);
            }
        }
    }

    int r0 = q * 4;
#pragma unroll
    for (int rf = 0; rf < 4; rf++) {
#pragma unroll
        for (int i = 0; i < 4; i++) {
            int row = rowBase + wr * 64 + rf * 16 + r0 + i;
            if (row >= N) continue;
#pragma unroll
            for (int cf = 0; cf < 4; cf++) {
                float v = acc[rf][cf][i];
                if (RELU) v = fmaxf(v, 0.f);
                Out[(long)row * NOUT + colBase + wc * 64 + cf * 16 + m] = (bf16_t)v;
            }
        }
    }
}

// ---------- direct-load MFMA GEMM (layer 3 only: NOUT=48, small) ----------
template <int CF, bool RELU>
__global__ __launch_bounds__(256) void gemm_mfma(
    const bf16_t* __restrict__ A1, const bf16_t* __restrict__ W1,
    float* __restrict__ Out, int N, int K, int NOUT) {
    const int G = NOUT / (16 * CF);
    int lane = threadIdx.x & 63;
    int wid = blockIdx.x * 4 + (threadIdx.x >> 6);
    int rowTile = wid / G;
    int cg = wid - rowTile * G;
    int rowBase = rowTile * 64;
    if (rowBase >= N) return;
    int colBase = cg * 16 * CF;
    int m = lane & 15;
    int kq = (lane >> 4) * 8;

    f32x4 acc[4][CF];
#pragma unroll
    for (int a = 0; a < 4; a++)
#pragma unroll
        for (int b = 0; b < CF; b++) acc[a][b] = (f32x4){0.f, 0.f, 0.f, 0.f};

    long ar[4];
#pragma unroll
    for (int rf = 0; rf < 4; rf++) {
        int r = rowBase + rf * 16 + m;
        ar[rf] = (long)min(r, N - 1) * K;
    }

    for (int k0 = kq; k0 < K; k0 += 32) {
        bf16x8 a[4], b[CF];
#pragma unroll
        for (int rf = 0; rf < 4; rf++) a[rf] = *(const bf16x8*)(A1 + ar[rf] + k0);
#pragma unroll
        for (int cf = 0; cf < CF; cf++)
            b[cf] = *(const bf16x8*)(W1 + (long)(colBase + cf * 16 + m) * K + k0);
#pragma unroll
        for (int rf = 0; rf < 4; rf++)
#pragma unroll
            for (int cf = 0; cf < CF; cf++)
                acc[rf][cf] = __builtin_amdgcn_mfma_f32_16x16x32_bf16(a[rf], b[cf], acc[rf][cf], 0, 0, 0);
    }

    int r0 = (lane >> 4) * 4;
#pragma unroll
    for (int rf = 0; rf < 4; rf++) {
#pragma unroll
        for (int i = 0; i < 4; i++) {
            int row = rowBase + rf * 16 + r0 + i;
            if (row >= N) continue;
#pragma unroll
            for (int cf = 0; cf < CF; cf++) {
                float v = acc[rf][cf][i];
                if (RELU) v = fmaxf(v, 0.f);
                Out[(long)row * NOUT + colBase + cf * 16 + m] = v;
            }
        }
    }
}

// ---------- final: gather-agg T3 (48 cols) + dinv + R3 + log_softmax, 1 wave/row ----------
__global__ void final_fused(const int* __restrict__ rowptr, const int* __restrict__ csr_src,
                            const float* __restrict__ T3, const float* __restrict__ R3,
                            const float* __restrict__ dinv, float* __restrict__ out, int N) {
    int wid = blockIdx.x * (blockDim.x >> 6) + (threadIdx.x >> 6);
    int lane = threadIdx.x & 63;
    if (wid >= N) return;
    int s0 = rowptr[wid], s1 = rowptr[wid + 1];
    float a = 0.f, b = 0.f;
    if (lane < 48) {
        int j = s0;
        for (; j + 3 < s1; j += 4) {
            int sa = csr_src[j], sb = csr_src[j + 1], sc = csr_src[j + 2], sd = csr_src[j + 3];
            a += T3[(long)sa * 48 + lane] + T3[(long)sb * 48 + lane];
            b += T3[(long)sc * 48 + lane] + T3[(long)sd * 48 + lane];
        }
        for (; j < s1; j++) a += T3[(long)csr_src[j] * 48 + lane];
    }
    bool act = lane < 47;
    float v = act ? (a + b) * dinv[wid] + R3[(long)wid * 48 + lane] : -INFINITY;
    float mx = v;
#pragma unroll
    for (int o = 32; o; o >>= 1) mx = fmaxf(mx, __shfl_xor(mx, o));
    float ex = act ? expf(v - mx) : 0.f;
    float s = ex;
#pragma unroll
    for (int o = 32; o; o >>= 1) s += __shfl_xor(s, o);
    float ls = logf(s);
    if (act) out[(long)wid * 47 + lane] = v - mx - ls;
}

extern "C" void kernel_launch(void* const* d_in, const int* in_sizes, int n_in,
                              void* d_out, int out_size, void* d_ws, size_t ws_size,
                              hipStream_t stream) {
    const float* x   = (const float*)d_in[0];
    const float* Wl1 = (const float*)d_in[1];
    const float* Wr1 = (const float*)d_in[2];
    const float* Wl2 = (const float*)d_in[3];
    const float* Wr2 = (const float*)d_in[4];
    const float* Wl3 = (const float*)d_in[5];
    const float* Wr3 = (const float*)d_in[6];
    const int*   ei  = (const int*)d_in[7];
    float* out = (float*)d_out;
    const int N = NN, E = NE;
    const int NB = (N + 1023) / 1024;

    char* ws = (char*)d_ws;
    size_t off = 0;
    auto carve = [&](size_t bytes) { void* p = ws + off; off = (off + bytes + 255) & ~(size_t)255; return p; };
    int*    degi     = (int*)carve((size_t)N * 4);
    int*    rowptr   = (int*)carve((size_t)(N + 1) * 4);
    int*    cursor   = (int*)carve((size_t)N * 4);
    int*    csr_src  = (int*)carve((size_t)E * 4);
    int*    partials = (int*)carve(64 * 4);
    int*    blockofs = (int*)carve(64 * 4);
    float*  dinv     = (float*)carve((size_t)N * 4);
    bf16_t* aggB     = (bf16_t*)carve((size_t)N * 256 * 2);
    bf16_t* xB       = (bf16_t*)carve((size_t)N * 128 * 2);
    bf16_t* H1       = (bf16_t*)carve((size_t)N * 256 * 2);
    bf16_t* H2       = (bf16_t*)carve((size_t)N * 256 * 2);
    float*  T3       = (float*)carve((size_t)N * 48 * 4);
    float*  R3       = (float*)carve((size_t)N * 48 * 4);
    bf16_t* wb1l = (bf16_t*)carve(256 * 128 * 2);
    bf16_t* wb1r = (bf16_t*)carve(256 * 128 * 2);
    bf16_t* wb2l = (bf16_t*)carve(256 * 256 * 2);
    bf16_t* wb2r = (bf16_t*)carve(256 * 256 * 2);
    bf16_t* wb3l = (bf16_t*)carve(48 * 256 * 2);
    bf16_t* wb3r = (bf16_t*)carve(48 * 256 * 2);

    // --- converts ---
    cvt_f32_bf16<<<(N * 32 + 255) / 256, 256, 0, stream>>>(x, xB, N * 32);
    cvt_f32_bf16<<<32, 256, 0, stream>>>(Wl1, wb1l, 256 * 32);
    cvt_f32_bf16<<<32, 256, 0, stream>>>(Wr1, wb1r, 256 * 32);
    cvt_f32_bf16<<<64, 256, 0, stream>>>(Wl2, wb2l, 256 * 64);
    cvt_f32_bf16<<<64, 256, 0, stream>>>(Wr2, wb2r, 256 * 64);
    cvt_pad_w3<<<12, 256, 0, stream>>>(Wl3, wb3l);
    cvt_pad_w3<<<12, 256, 0, stream>>>(Wr3, wb3r);

    // --- CSR build ---
    hipMemsetAsync(degi, 0, (size_t)N * 4, stream);
    deg_count<<<(E + 255) / 256, 256, 0, stream>>>(ei, degi, E);
    scan_blocks<<<NB, 1024, 0, stream>>>(degi, rowptr, dinv, partials, N);
    scan_partials<<<1, 64, 0, stream>>>(partials, blockofs, rowptr, NB, N);
    add_offsets<<<(N + 255) / 256, 256, 0, stream>>>(rowptr, cursor, blockofs, N);
    fill_csr<<<(E + 255) / 256, 256, 0, stream>>>(ei, cursor, csr_src, E);

    const int RT = (N + 127) / 128;  // 391 row tiles

    // --- layer 1 ---
    gather_agg_128<<<(N + 3) / 4, 256, 0, stream>>>(rowptr, csr_src, x, dinv, aggB, N);
    gemm_lds<128, true, true><<<dim3(RT, 2), 256, 0, stream>>>(aggB, xB, wb1l, wb1r, H1, N, 256);

    // --- layer 2 ---
    gather_agg_256<<<(N + 3) / 4, 256, 0, stream>>>(rowptr, csr_src, H1, dinv, aggB, N);
    gemm_lds<256, true, true><<<dim3(RT, 2), 256, 0, stream>>>(aggB, H1, wb2l, wb2r, H2, N, 256);

    // --- layer 3: matmuls first (agg is linear), then fused gather+log_softmax ---
    gemm_mfma<3, false><<<196, 256, 0, stream>>>(H2, wb3l, T3, N, 256, 48);
    gemm_mfma<3, false><<<196, 256, 0, stream>>>(H2, wb3r, R3, N, 256, 48);
    final_fused<<<(N + 3) / 4, 256, 0, stream>>>(rowptr, csr_src, T3, R3, dinv, out, N);
}

// Round 5
// 323.153 us; speedup vs baseline: 18.0510x; 1.1067x over previous
//
#include <hip/hip_runtime.h>
#include <hip/hip_bf16.h>

typedef __bf16 bf16_t;
typedef __bf16 bf16x8 __attribute__((ext_vector_type(8)));
typedef __bf16 bf16x4 __attribute__((ext_vector_type(4)));
typedef __bf16 bf16x2 __attribute__((ext_vector_type(2)));
typedef float f32x4 __attribute__((ext_vector_type(4)));

#define NN 50000
#define NE 600000

__device__ __forceinline__ void gload_lds16(const void* g, void* l) {
    __builtin_amdgcn_global_load_lds(
        (const __attribute__((address_space(1))) void*)g,
        (__attribute__((address_space(3))) void*)l, 16, 0, 0);
}

// ---------- converts ----------
__global__ void cvt_f32_bf16(const float* __restrict__ in, bf16_t* __restrict__ out, int n4) {
    int t = blockIdx.x * blockDim.x + threadIdx.x;
    if (t >= n4) return;
    float4 v = ((const float4*)in)[t];
    bf16x4 o; o[0] = (bf16_t)v.x; o[1] = (bf16_t)v.y; o[2] = (bf16_t)v.z; o[3] = (bf16_t)v.w;
    ((bf16x4*)out)[t] = o;
}

// all six weight matrices in one kernel (4-elem groups; W3 zero-padded 47->48 rows)
__global__ void cvt_weights(const float* __restrict__ Wl1, const float* __restrict__ Wr1,
                            const float* __restrict__ Wl2, const float* __restrict__ Wr2,
                            const float* __restrict__ Wl3, const float* __restrict__ Wr3,
                            bf16_t* __restrict__ o1l, bf16_t* __restrict__ o1r,
                            bf16_t* __restrict__ o2l, bf16_t* __restrict__ o2r,
                            bf16_t* __restrict__ o3l, bf16_t* __restrict__ o3r) {
    int t = blockIdx.x * blockDim.x + threadIdx.x;  // group id, 55296 total
    const float* in; bf16_t* out; int g;
    if (t < 8192)       { in = Wl1; out = o1l; g = t; }
    else if (t < 16384) { in = Wr1; out = o1r; g = t - 8192; }
    else if (t < 32768) { in = Wl2; out = o2l; g = t - 16384; }
    else if (t < 49152) { in = Wr2; out = o2r; g = t - 32768; }
    else if (t < 52224) { in = Wl3; out = o3l; g = t - 49152; }
    else if (t < 55296) { in = Wr3; out = o3r; g = t - 52224; }
    else return;
    bf16x4 o;
    if (in == Wl3 || in == Wr3) {
        int row = g >> 6, c4 = (g & 63) * 4;  // out row among 48
        if (row < 47) {
            float4 v = *(const float4*)(in + row * 256 + c4);
            o[0] = (bf16_t)v.x; o[1] = (bf16_t)v.y; o[2] = (bf16_t)v.z; o[3] = (bf16_t)v.w;
        } else {
            o[0] = o[1] = o[2] = o[3] = (bf16_t)0.f;
        }
        *(bf16x4*)(out + row * 256 + c4) = o;
    } else {
        float4 v = ((const float4*)in)[g];
        o[0] = (bf16_t)v.x; o[1] = (bf16_t)v.y; o[2] = (bf16_t)v.z; o[3] = (bf16_t)v.w;
        ((bf16x4*)out)[g] = o;
    }
}

// ---------- CSR build ----------
__global__ void deg_count(const int* __restrict__ ei, int* __restrict__ degi, int E) {
    int e = blockIdx.x * blockDim.x + threadIdx.x;
    if (e < E) atomicAdd(&degi[ei[E + e]], 1);
}

__global__ __launch_bounds__(1024) void scan_blocks(const int* __restrict__ degi,
                                                    int* __restrict__ rowptr,
                                                    float* __restrict__ dinv,
                                                    int* __restrict__ partials, int n) {
    int i = blockIdx.x * 1024 + threadIdx.x;
    int v = (i < n) ? degi[i] : 0;
    int lane = threadIdx.x & 63;
    int w = threadIdx.x >> 6;
    int s = v;
#pragma unroll
    for (int o = 1; o < 64; o <<= 1) {
        int t = __shfl_up(s, o);
        if (lane >= o) s += t;
    }
    __shared__ int wsum[16];
    if (lane == 63) wsum[w] = s;
    __syncthreads();
    if (threadIdx.x < 16) {
        int t = wsum[threadIdx.x];
#pragma unroll
        for (int o = 1; o < 16; o <<= 1) {
            int u = __shfl_up(t, o);
            if ((int)threadIdx.x >= o) t += u;
        }
        wsum[threadIdx.x] = t;
    }
    __syncthreads();
    int incl = s + ((w > 0) ? wsum[w - 1] : 0);
    if (i < n) {
        rowptr[i] = incl - v;
        dinv[i] = 1.0f / fmaxf((float)v, 1.0f);
    }
    if (threadIdx.x == 1023) partials[blockIdx.x] = incl;
}

__global__ void scan_partials(const int* __restrict__ partials, int* __restrict__ blockofs,
                              int* __restrict__ rowptr, int nb, int n) {
    int lane = threadIdx.x;
    int v = (lane < nb) ? partials[lane] : 0;
    int s = v;
#pragma unroll
    for (int o = 1; o < 64; o <<= 1) {
        int t = __shfl_up(s, o);
        if (lane >= o) s += t;
    }
    if (lane < nb) blockofs[lane] = s - v;
    if (lane == 63) rowptr[n] = s;
}

__global__ void add_offsets(int* __restrict__ rowptr, int* __restrict__ cursor,
                            const int* __restrict__ blockofs, int n) {
    int i = blockIdx.x * blockDim.x + threadIdx.x;
    if (i >= n) return;
    int v = rowptr[i] + blockofs[i >> 10];
    rowptr[i] = v;
    cursor[i] = v;
}

__global__ void fill_csr(const int* __restrict__ ei, int* __restrict__ cursor,
                         int* __restrict__ csr_src, int E) {
    int e = blockIdx.x * blockDim.x + threadIdx.x;
    if (e >= E) return;
    int d = ei[E + e];
    int pos = atomicAdd(&cursor[d], 1);
    csr_src[pos] = ei[e];
}

// ---------- gather aggregations (half-wave per dst node, 2 dst/wave) ----------
// C=128 bf16 source (xB). 32 lanes x bf16x4 (8B) = full 256B row per iter.
__global__ void gather_agg_128(const int* __restrict__ rowptr, const int* __restrict__ csr_src,
                               const bf16_t* __restrict__ X, const float* __restrict__ dinv,
                               bf16_t* __restrict__ out, int N) {
    int wv = blockIdx.x * (blockDim.x >> 6) + (threadIdx.x >> 6);
    int lane = threadIdx.x & 63;
    int node = wv * 2 + (lane >> 5);
    if (node >= N) return;
    int sub = lane & 31;
    int c = sub * 4;
    int s0 = rowptr[node], s1 = rowptr[node + 1];
    float acc[4] = {0.f, 0.f, 0.f, 0.f};
    int j = s0;
    for (; j + 3 < s1; j += 4) {
        int sa = csr_src[j], sb = csr_src[j + 1], sc = csr_src[j + 2], sd = csr_src[j + 3];
        bf16x4 va = *(const bf16x4*)(X + (long)sa * 128 + c);
        bf16x4 vb = *(const bf16x4*)(X + (long)sb * 128 + c);
        bf16x4 vc = *(const bf16x4*)(X + (long)sc * 128 + c);
        bf16x4 vd = *(const bf16x4*)(X + (long)sd * 128 + c);
#pragma unroll
        for (int i = 0; i < 4; i++)
            acc[i] += ((float)va[i] + (float)vb[i]) + ((float)vc[i] + (float)vd[i]);
    }
    for (; j < s1; j++) {
        int sa = csr_src[j];
        bf16x4 va = *(const bf16x4*)(X + (long)sa * 128 + c);
#pragma unroll
        for (int i = 0; i < 4; i++) acc[i] += (float)va[i];
    }
    float di = dinv[node];
    bf16x4 o;
#pragma unroll
    for (int i = 0; i < 4; i++) o[i] = (bf16_t)(acc[i] * di);
    *(bf16x4*)(out + (long)node * 128 + c) = o;
}

// C=256 bf16 source. 32 lanes x bf16x8 (16B) = full 512B row per iter.
__global__ void gather_agg_256(const int* __restrict__ rowptr, const int* __restrict__ csr_src,
                               const bf16_t* __restrict__ H, const float* __restrict__ dinv,
                               bf16_t* __restrict__ out, int N) {
    int wv = blockIdx.x * (blockDim.x >> 6) + (threadIdx.x >> 6);
    int lane = threadIdx.x & 63;
    int node = wv * 2 + (lane >> 5);
    if (node >= N) return;
    int sub = lane & 31;
    int c = sub * 8;
    int s0 = rowptr[node], s1 = rowptr[node + 1];
    float acc[8] = {0.f, 0.f, 0.f, 0.f, 0.f, 0.f, 0.f, 0.f};
    int j = s0;
    for (; j + 1 < s1; j += 2) {
        int sa = csr_src[j], sb = csr_src[j + 1];
        bf16x8 va = *(const bf16x8*)(H + (long)sa * 256 + c);
        bf16x8 vb = *(const bf16x8*)(H + (long)sb * 256 + c);
#pragma unroll
        for (int i = 0; i < 8; i++) acc[i] += (float)va[i] + (float)vb[i];
    }
    if (j < s1) {
        int sa = csr_src[j];
        bf16x8 va = *(const bf16x8*)(H + (long)sa * 256 + c);
#pragma unroll
        for (int i = 0; i < 8; i++) acc[i] += (float)va[i];
    }
    float di = dinv[node];
    bf16x8 o;
#pragma unroll
    for (int i = 0; i < 8; i++) o[i] = (bf16_t)(acc[i] * di);
    *(bf16x8*)(out + (long)node * 256 + c) = o;
}

// ---------- LDS-staged MFMA GEMM: 128x128 tile / block, BK=64 slices ----------
template <int KTOT, bool DUAL, bool RELU>
__global__ __launch_bounds__(256) void gemm_lds(
    const bf16_t* __restrict__ A1, const bf16_t* __restrict__ A2,
    const bf16_t* __restrict__ W1, const bf16_t* __restrict__ W2,
    bf16_t* __restrict__ Out, int N, int NOUT) {
    __shared__ bf16_t As[128 * 64];
    __shared__ bf16_t Bs[128 * 64];
    int tid = threadIdx.x;
    int w = tid >> 6, lane = tid & 63;
    int wr = w >> 1, wc = w & 1;
    int rowBase = blockIdx.x * 128;
    int colBase = blockIdx.y * 128;
    int m = lane & 15, q = lane >> 4;

    long aoff[4], boff[4];
    int ldsOff[4];
#pragma unroll
    for (int i = 0; i < 4; i++) {
        int c = w * 256 + i * 64 + lane;
        int r = c >> 3, s = c & 7;
        int gk = (s ^ (r & 7)) << 3;
        aoff[i] = (long)min(rowBase + r, N - 1) * KTOT + gk;
        boff[i] = (long)(colBase + r) * KTOT + gk;
        ldsOff[i] = (w * 4 + i) * 512;
    }

    f32x4 acc[4][4];
#pragma unroll
    for (int a = 0; a < 4; a++)
#pragma unroll
        for (int b = 0; b < 4; b++) acc[a][b] = (f32x4){0.f, 0.f, 0.f, 0.f};

#pragma unroll
    for (int half = 0; half < (DUAL ? 2 : 1); half++) {
        const bf16_t* A = half ? A2 : A1;
        const bf16_t* W = half ? W2 : W1;
#pragma unroll
        for (int k0 = 0; k0 < KTOT; k0 += 64) {
            __syncthreads();
#pragma unroll
            for (int i = 0; i < 4; i++) {
                gload_lds16(A + aoff[i] + k0, As + ldsOff[i]);
                gload_lds16(W + boff[i] + k0, Bs + ldsOff[i]);
            }
            __syncthreads();
#pragma unroll
            for (int ks = 0; ks < 2; ks++) {
                bf16x8 af[4], bfr[4];
#pragma unroll
                for (int rf = 0; rf < 4; rf++) {
                    int r = wr * 64 + rf * 16 + m;
                    int seg = ks * 4 + q;
                    af[rf] = *(const bf16x8*)(As + r * 64 + ((seg ^ (r & 7)) << 3));
                }
#pragma unroll
                for (int cf = 0; cf < 4; cf++) {
                    int r = wc * 64 + cf * 16 + m;
                    int seg = ks * 4 + q;
                    bfr[cf] = *(const bf16x8*)(Bs + r * 64 + ((seg ^ (r & 7)) << 3));
                }
#pragma unroll
                for (int rf = 0; rf < 4; rf++)
#pragma unroll
                    for (int cf = 0; cf < 4; cf++)
                        acc[rf][cf] = __builtin_amdgcn_mfma_f32_16x16x32_bf16(af[rf], bfr[cf], acc[rf][cf], 0, 0, 0);
            }
        }
    }

    int r0 = q * 4;
#pragma unroll
    for (int rf = 0; rf < 4; rf++) {
#pragma unroll
        for (int i = 0; i < 4; i++) {
            int row = rowBase + wr * 64 + rf * 16 + r0 + i;
            if (row >= N) continue;
#pragma unroll
            for (int cf = 0; cf < 4; cf++) {
                float v = acc[rf][cf][i];
                if (RELU) v = fmaxf(v, 0.f);
                Out[(long)row * NOUT + colBase + wc * 64 + cf * 16 + m] = (bf16_t)v;
            }
        }
    }
}

// ---------- direct-load MFMA GEMM (layer 3: NOUT=48) ----------
template <int CF, bool OUT_BF16>
__global__ __launch_bounds__(256) void gemm_mfma(
    const bf16_t* __restrict__ A1, const bf16_t* __restrict__ W1,
    void* __restrict__ Out, int N, int K, int NOUT) {
    const int G = NOUT / (16 * CF);
    int lane = threadIdx.x & 63;
    int wid = blockIdx.x * 4 + (threadIdx.x >> 6);
    int rowTile = wid / G;
    int cg = wid - rowTile * G;
    int rowBase = rowTile * 64;
    if (rowBase >= N) return;
    int colBase = cg * 16 * CF;
    int m = lane & 15;
    int kq = (lane >> 4) * 8;

    f32x4 acc[4][CF];
#pragma unroll
    for (int a = 0; a < 4; a++)
#pragma unroll
        for (int b = 0; b < CF; b++) acc[a][b] = (f32x4){0.f, 0.f, 0.f, 0.f};

    long ar[4];
#pragma unroll
    for (int rf = 0; rf < 4; rf++) {
        int r = rowBase + rf * 16 + m;
        ar[rf] = (long)min(r, N - 1) * K;
    }

    for (int k0 = kq; k0 < K; k0 += 32) {
        bf16x8 a[4], b[CF];
#pragma unroll
        for (int rf = 0; rf < 4; rf++) a[rf] = *(const bf16x8*)(A1 + ar[rf] + k0);
#pragma unroll
        for (int cf = 0; cf < CF; cf++)
            b[cf] = *(const bf16x8*)(W1 + (long)(colBase + cf * 16 + m) * K + k0);
#pragma unroll
        for (int rf = 0; rf < 4; rf++)
#pragma unroll
            for (int cf = 0; cf < CF; cf++)
                acc[rf][cf] = __builtin_amdgcn_mfma_f32_16x16x32_bf16(a[rf], b[cf], acc[rf][cf], 0, 0, 0);
    }

    int r0 = (lane >> 4) * 4;
#pragma unroll
    for (int rf = 0; rf < 4; rf++) {
#pragma unroll
        for (int i = 0; i < 4; i++) {
            int row = rowBase + rf * 16 + r0 + i;
            if (row >= N) continue;
#pragma unroll
            for (int cf = 0; cf < CF; cf++) {
                float v = acc[rf][cf][i];
                int col = colBase + cf * 16 + m;
                if (OUT_BF16)
                    ((bf16_t*)Out)[(long)row * NOUT + col] = (bf16_t)v;
                else
                    ((float*)Out)[(long)row * NOUT + col] = v;
            }
        }
    }
}

// ---------- final: gather-agg T3 (bf16, 48 cols) + dinv + R3 + log_softmax ----------
__global__ void final_fused(const int* __restrict__ rowptr, const int* __restrict__ csr_src,
                            const bf16_t* __restrict__ T3, const float* __restrict__ R3,
                            const float* __restrict__ dinv, float* __restrict__ out, int N) {
    int wid = blockIdx.x * (blockDim.x >> 6) + (threadIdx.x >> 6);
    int lane = threadIdx.x & 63;
    if (wid >= N) return;
    int s0 = rowptr[wid], s1 = rowptr[wid + 1];
    float a = 0.f, b = 0.f;
    if (lane < 48) {
        int j = s0;
        for (; j + 3 < s1; j += 4) {
            int sa = csr_src[j], sb = csr_src[j + 1], sc = csr_src[j + 2], sd = csr_src[j + 3];
            a += (float)T3[(long)sa * 48 + lane] + (float)T3[(long)sb * 48 + lane];
            b += (float)T3[(long)sc * 48 + lane] + (float)T3[(long)sd * 48 + lane];
        }
        for (; j < s1; j++) a += (float)T3[(long)csr_src[j] * 48 + lane];
    }
    bool act = lane < 47;
    float v = act ? (a + b) * dinv[wid] + R3[(long)wid * 48 + lane] : -INFINITY;
    float mx = v;
#pragma unroll
    for (int o = 32; o; o >>= 1) mx = fmaxf(mx, __shfl_xor(mx, o));
    float ex = act ? expf(v - mx) : 0.f;
    float s = ex;
#pragma unroll
    for (int o = 32; o; o >>= 1) s += __shfl_xor(s, o);
    float ls = logf(s);
    if (act) out[(long)wid * 47 + lane] = v - mx - ls;
}

extern "C" void kernel_launch(void* const* d_in, const int* in_sizes, int n_in,
                              void* d_out, int out_size, void* d_ws, size_t ws_size,
                              hipStream_t stream) {
    const float* x   = (const float*)d_in[0];
    const float* Wl1 = (const float*)d_in[1];
    const float* Wr1 = (const float*)d_in[2];
    const float* Wl2 = (const float*)d_in[3];
    const float* Wr2 = (const float*)d_in[4];
    const float* Wl3 = (const float*)d_in[5];
    const float* Wr3 = (const float*)d_in[6];
    const int*   ei  = (const int*)d_in[7];
    float* out = (float*)d_out;
    const int N = NN, E = NE;
    const int NB = (N + 1023) / 1024;

    char* ws = (char*)d_ws;
    size_t off = 0;
    auto carve = [&](size_t bytes) { void* p = ws + off; off = (off + bytes + 255) & ~(size_t)255; return p; };
    int*    degi     = (int*)carve((size_t)N * 4);
    int*    rowptr   = (int*)carve((size_t)(N + 1) * 4);
    int*    cursor   = (int*)carve((size_t)N * 4);
    int*    csr_src  = (int*)carve((size_t)E * 4);
    int*    partials = (int*)carve(64 * 4);
    int*    blockofs = (int*)carve(64 * 4);
    float*  dinv     = (float*)carve((size_t)N * 4);
    bf16_t* aggB     = (bf16_t*)carve((size_t)N * 256 * 2);
    bf16_t* xB       = (bf16_t*)carve((size_t)N * 128 * 2);
    bf16_t* H1       = (bf16_t*)carve((size_t)N * 256 * 2);
    bf16_t* H2       = (bf16_t*)carve((size_t)N * 256 * 2);
    bf16_t* T3       = (bf16_t*)carve((size_t)N * 48 * 2);
    float*  R3       = (float*)carve((size_t)N * 48 * 4);
    bf16_t* wb1l = (bf16_t*)carve(256 * 128 * 2);
    bf16_t* wb1r = (bf16_t*)carve(256 * 128 * 2);
    bf16_t* wb2l = (bf16_t*)carve(256 * 256 * 2);
    bf16_t* wb2r = (bf16_t*)carve(256 * 256 * 2);
    bf16_t* wb3l = (bf16_t*)carve(48 * 256 * 2);
    bf16_t* wb3r = (bf16_t*)carve(48 * 256 * 2);

    // --- converts ---
    cvt_f32_bf16<<<(N * 32 + 255) / 256, 256, 0, stream>>>(x, xB, N * 32);
    cvt_weights<<<216, 256, 0, stream>>>(Wl1, Wr1, Wl2, Wr2, Wl3, Wr3,
                                         wb1l, wb1r, wb2l, wb2r, wb3l, wb3r);

    // --- CSR build ---
    hipMemsetAsync(degi, 0, (size_t)N * 4, stream);
    deg_count<<<(E + 255) / 256, 256, 0, stream>>>(ei, degi, E);
    scan_blocks<<<NB, 1024, 0, stream>>>(degi, rowptr, dinv, partials, N);
    scan_partials<<<1, 64, 0, stream>>>(partials, blockofs, rowptr, NB, N);
    add_offsets<<<(N + 255) / 256, 256, 0, stream>>>(rowptr, cursor, blockofs, N);
    fill_csr<<<(E + 255) / 256, 256, 0, stream>>>(ei, cursor, csr_src, E);

    const int RT = (N + 127) / 128;

    // --- layer 1 (gathers from xB: bf16 halves traffic) ---
    gather_agg_128<<<(N / 2 + 3) / 4, 256, 0, stream>>>(rowptr, csr_src, xB, dinv, aggB, N);
    gemm_lds<128, true, true><<<dim3(RT, 2), 256, 0, stream>>>(aggB, xB, wb1l, wb1r, H1, N, 256);

    // --- layer 2 ---
    gather_agg_256<<<(N / 2 + 3) / 4, 256, 0, stream>>>(rowptr, csr_src, H1, dinv, aggB, N);
    gemm_lds<256, true, true><<<dim3(RT, 2), 256, 0, stream>>>(aggB, H1, wb2l, wb2r, H2, N, 256);

    // --- layer 3: matmuls first (agg is linear), then fused gather+log_softmax ---
    gemm_mfma<3, true><<<196, 256, 0, stream>>>(H2, wb3l, T3, N, 256, 48);
    gemm_mfma<3, false><<<196, 256, 0, stream>>>(H2, wb3r, R3, N, 256, 48);
    final_fused<<<(N + 3) / 4, 256, 0, stream>>>(rowptr, csr_src, T3, R3, dinv, out, N);
}